// Round 15
// baseline (52.581 us; speedup 1.0000x reference)
//
#include <hip/hip_runtime.h>

#define N 8192
#define BLOCK 128
#define ITILE 128                  // 1 i-point per thread
#define NB (N / ITILE)             // 64
#define NTRI (NB * (NB + 1) / 2)   // 2080 triangular tiles
#define JSPLIT 4
#define JSUB (ITILE / JSPLIT)      // 32 j-points per block
#define NPART (NTRI * JSPLIT)      // 8320 partials

// Position-histogram binning for the smooth H8 part.
#define BGRID 64
#define BINV 6.4f                  // 1/h, h = 10/64
#define NBINS (BGRID * BGRID)      // 4096
#define FDIM 127                   // signed bin offsets -63..63
#define FSIZE (FDIM * FDIM)        // 16129
#define FH 0.15625f                // 10/64

#define FBLOCKS 64
#define HISTBLOCKS 4
#define KEBLOCKS 8
#define CORRBX 32                  // corr blocks = CORRBX*JSPLIT = 128

// ws layout (float-index offsets)
#define WS_F 0                     // 16129 floats (pad to 16384)
#define WS_HIST 16384              // 4*4096 u32
#define WS_PART 33280              // 8320 floats
#define WS_CORR 41728              // 128 floats
#define WS_KE 41920                // 8 floats

#define RSQ __builtin_amdgcn_rsqf

typedef float f32x2 __attribute__((ext_vector_type(2)));

__device__ __forceinline__ f32x2 rsqv(f32x2 a) {
    f32x2 r = {RSQ(a.x), RSQ(a.y)};
    return r;
}

// prep: blocks [0,64): F table = H8 at signed bin offsets (skip the min image);
//       blocks [64,68): position histogram (LDS atomics, 4 partial copies);
//       blocks [68,76): KE partial sums.
__global__ __launch_bounds__(256) void prep_kernel(const float* __restrict__ xy,
                                                   const float* __restrict__ pxy,
                                                   float* __restrict__ F,
                                                   unsigned* __restrict__ hist,
                                                   float* __restrict__ ke_part) {
    const int t = threadIdx.x;
    const int b = blockIdx.x;
    if (b < FBLOCKS) {
        int k = b * 256 + t;
        if (k < FSIZE) {
            float a  = (float)(k % FDIM - 63) * FH;
            float bb = (float)(k / FDIM - 63) * FH;
            int ixm = (__builtin_fabsf(a)  <= 5.0f) ? 0 : (a  > 0.0f ? -1 : 1);
            int iym = (__builtin_fabsf(bb) <= 5.0f) ? 0 : (bb > 0.0f ? -1 : 1);
            float s = 0.0f;
            for (int iy = -1; iy <= 1; ++iy)
                for (int ix = -1; ix <= 1; ++ix) {
                    if (ix == ixm && iy == iym) continue;   // drop min image
                    float xs = __builtin_fmaf(10.0f, (float)ix, a);
                    float ys = __builtin_fmaf(10.0f, (float)iy, bb);
                    s += RSQ(xs * xs + ys * ys);
                }
            F[k] = s;
        }
    } else if (b < FBLOCKS + HISTBLOCKS) {
        __shared__ unsigned lh[NBINS];
        const int hb = b - FBLOCKS;
        for (int k = t; k < NBINS; k += 256) lh[k] = 0u;
        __syncthreads();
        const float2* p2 = (const float2*)xy;
        for (int r = 0; r < 8; ++r) {
            float2 p = p2[hb * 2048 + r * 256 + t];
            int cx = (int)(p.x * BINV); cx = cx > 63 ? 63 : cx;
            int cy = (int)(p.y * BINV); cy = cy > 63 ? 63 : cy;
            atomicAdd(&lh[cy * BGRID + cx], 1u);
        }
        __syncthreads();
        for (int k = t; k < NBINS; k += 256) hist[hb * NBINS + k] = lh[k];
    } else {
        const int kb = b - FBLOCKS - HISTBLOCKS;
        const float4* p4 = (const float4*)pxy;
        float acc = 0.0f;
        for (int k = kb * 256 + t; k < (2 * N) / 4; k += KEBLOCKS * 256) {
            float4 v = p4[k];
            acc += 0.5f * (v.x * v.x + v.y * v.y + v.z * v.z + v.w * v.w);
        }
        for (int off = 32; off > 0; off >>= 1)
            acc += __shfl_down(acc, off, 64);
        __shared__ float ws[4];
        if ((t & 63) == 0) ws[t >> 6] = acc;
        __syncthreads();
        if (t == 0) ke_part[kb] = (ws[0] + ws[1]) + (ws[2] + ws[3]);
    }
}

// main: blocks bx<CORRBX: binned H8 autocorrelation (overlaps with pe);
//       else: exact min-image 1/r over triangular 128x128 tiles (j-split 4).
__global__ __launch_bounds__(BLOCK) void main_kernel(const float* __restrict__ xy,
                                                     const float* __restrict__ F,
                                                     const unsigned* __restrict__ hist,
                                                     float* __restrict__ partial,
                                                     float* __restrict__ corr_part) {
    const int t = threadIdx.x;
    __shared__ float wsum[BLOCK / 64];

    if (blockIdx.x < CORRBX) {
        // corr block cid: y1 row of bins x half of y2 range
        const int cid = blockIdx.x * JSPLIT + blockIdx.y;   // 0..127
        const int y1 = cid >> 1;
        const int y2base = (cid & 1) * 32;
        __shared__ float n2row[BGRID];
        const int x1 = t & 63;
        const int x2c = t >> 6;                              // 0 or 1
        float n1 = (float)(hist[y1 * BGRID + x1]
                         + hist[NBINS + y1 * BGRID + x1]
                         + hist[2 * NBINS + y1 * BGRID + x1]
                         + hist[3 * NBINS + y1 * BGRID + x1]);
        float acc = 0.0f;
        for (int y2i = 0; y2i < 32; ++y2i) {
            const int yy = y2base + y2i;
            if (t < 64)
                n2row[t] = (float)(hist[yy * BGRID + t]
                                 + hist[NBINS + yy * BGRID + t]
                                 + hist[2 * NBINS + yy * BGRID + t]
                                 + hist[3 * NBINS + yy * BGRID + t]);
            __syncthreads();
            const int fbase = (y1 - yy + 63) * FDIM + 63 + x1;
            float s = 0.0f;
#pragma unroll 8
            for (int k = 0; k < 32; ++k) {
                int x2 = x2c * 32 + k;
                s = __builtin_fmaf(n2row[x2], F[fbase - x2], s);
            }
            acc += s;
            __syncthreads();
        }
        acc *= n1;
        for (int off = 32; off > 0; off >>= 1)
            acc += __shfl_down(acc, off, 64);
        if ((t & 63) == 0) wsum[t >> 6] = acc;
        __syncthreads();
        if (t == 0) corr_part[cid] = wsum[0] + wsum[1];
        return;
    }

    // ---- pe: exact min-image part ----
    int rem = blockIdx.x - CORRBX;
    int ib = 0;
    while (rem >= NB - ib) { rem -= NB - ib; ++ib; }
    const int jb = ib + rem;

    const int i = ib * ITILE + t;
    const float2 pi = ((const float2*)xy)[i];
    const f32x2 xiv = {pi.x, pi.x};
    const f32x2 yiv = {pi.y, pi.y};

    const int j0 = jb * ITILE + blockIdx.y * JSUB;
    const float4* __restrict__ xy4 = (const float4*)xy;     // (x0,y0,x1,y1) pairs
    const int jq = j0 >> 1;

    float a;
    if (ib == jb) {
        f32x2 acc = {0.0f, 0.0f};
#pragma unroll 8
        for (int q = 0; q < JSUB / 2; ++q) {
            float4 pj = xy4[jq + q];
            f32x2 dx = xiv - (f32x2){pj.x, pj.z};
            f32x2 dy = yiv - (f32x2){pj.y, pj.w};
            float tx0 = __builtin_fabsf(dx.x) - 5.0f;
            float tx1 = __builtin_fabsf(dx.y) - 5.0f;
            float ty0 = __builtin_fabsf(dy.x) - 5.0f;
            float ty1 = __builtin_fabsf(dy.y) - 5.0f;
            f32x2 ux = {5.0f - __builtin_fabsf(tx0), 5.0f - __builtin_fabsf(tx1)};
            f32x2 uy = {5.0f - __builtin_fabsf(ty0), 5.0f - __builtin_fabsf(ty1)};
            f32x2 r2 = __builtin_elementwise_fma(uy, uy, ux * ux);
            f32x2 rr = rsqv(r2);
            if (i == j0 + 2 * q)     rr.x = 0.0f;   // diagonal fully masked
            if (i == j0 + 2 * q + 1) rr.y = 0.0f;
            acc += rr;
        }
        a = acc.x + acc.y;
    } else {
        f32x2 s0 = {0.0f, 0.0f}, s1 = s0;
#pragma unroll 8
        for (int q = 0; q < JSUB / 2; ++q) {
            float4 pj = xy4[jq + q];                // uniform -> scalar broadcast
            f32x2 dx = xiv - (f32x2){pj.x, pj.z};
            f32x2 dy = yiv - (f32x2){pj.y, pj.w};
            float tx0 = __builtin_fabsf(dx.x) - 5.0f;
            float tx1 = __builtin_fabsf(dx.y) - 5.0f;
            float ty0 = __builtin_fabsf(dy.x) - 5.0f;
            float ty1 = __builtin_fabsf(dy.y) - 5.0f;
            f32x2 ux = {5.0f - __builtin_fabsf(tx0), 5.0f - __builtin_fabsf(tx1)};
            f32x2 uy = {5.0f - __builtin_fabsf(ty0), 5.0f - __builtin_fabsf(ty1)};
            f32x2 r2 = __builtin_elementwise_fma(uy, uy, ux * ux);
            if (q & 1) s1 += rsqv(r2);
            else       s0 += rsqv(r2);
        }
        f32x2 sv = s0 + s1;
        a = 2.0f * (sv.x + sv.y);                   // mirrored (j,i) tile
    }

    for (int off = 32; off > 0; off >>= 1)
        a += __shfl_down(a, off, 64);
    if ((t & 63) == 0) wsum[t >> 6] = a;
    __syncthreads();
    if (t == 0)
        partial[blockIdx.y * NTRI + (blockIdx.x - CORRBX)] = wsum[0] + wsum[1];
}

// finish: pe partials + corr partials + KE − N*F(0)  -> out scalar.
__global__ __launch_bounds__(1024) void finish_kernel(const float* __restrict__ partial,
                                                      const float* __restrict__ corr_part,
                                                      const float* __restrict__ ke_part,
                                                      const float* __restrict__ F,
                                                      float* __restrict__ out) {
    const int t = threadIdx.x;
    float acc = 0.0f;
    const float4* p4 = (const float4*)partial;
    for (int k = t; k < NPART / 4; k += 1024) {
        float4 v = p4[k];
        acc += (v.x + v.y) + (v.z + v.w);
    }
    if (t < 128) acc += corr_part[t];
    if (t < KEBLOCKS) acc += ke_part[t];
    if (t == 0) acc -= (float)N * F[63 * FDIM + 63];   // remove i==j from corr
    for (int off = 32; off > 0; off >>= 1)
        acc += __shfl_down(acc, off, 64);
    __shared__ float ws[16];
    if ((t & 63) == 0) ws[t >> 6] = acc;
    __syncthreads();
    if (t == 0) {
        float s = 0.0f;
        for (int w = 0; w < 16; ++w) s += ws[w];
        out[0] = s;
    }
}

extern "C" void kernel_launch(void* const* d_in, const int* in_sizes, int n_in,
                              void* d_out, int out_size, void* d_ws, size_t ws_size,
                              hipStream_t stream) {
    const float* xy  = (const float*)d_in[0];
    const float* pxy = (const float*)d_in[1];
    float* out       = (float*)d_out;
    float* wsf       = (float*)d_ws;
    float* F         = wsf + WS_F;
    unsigned* hist   = (unsigned*)(wsf + WS_HIST);
    float* partial   = wsf + WS_PART;
    float* corr_part = wsf + WS_CORR;
    float* ke_part   = wsf + WS_KE;

    prep_kernel<<<FBLOCKS + HISTBLOCKS + KEBLOCKS, 256, 0, stream>>>(xy, pxy, F, hist, ke_part);
    dim3 grid(CORRBX + NTRI, JSPLIT);
    main_kernel<<<grid, BLOCK, 0, stream>>>(xy, F, hist, partial, corr_part);
    finish_kernel<<<1, 1024, 0, stream>>>(partial, corr_part, ke_part, F, out);
}

// Round 16
// 26.415 us; speedup vs baseline: 1.9906x; 1.9906x over previous
//
#include <hip/hip_runtime.h>

#define N 8192
#define BLOCK 128
#define ITILE 128                  // 1 i-point per thread
#define NB (N / ITILE)             // 64
#define NTRI (NB * (NB + 1) / 2)   // 2080 triangular tiles
#define JSPLIT 4
#define JSUB (ITILE / JSPLIT)      // 32 j-points per block
#define NPART (NTRI * JSPLIT)      // 8320 partials

// Position-histogram binning for the smooth H8 part (all 8 non-min images, d>=5).
#define BGRID 64
#define BINV 6.4f                  // 1/h, h = 10/64
#define NBINS (BGRID * BGRID)      // 4096
#define FDIM 127                   // signed bin offsets -63..63
#define FSIZE (FDIM * FDIM)        // 16129
#define FH 0.15625f                // 10/64

#define FBLOCKS 64
#define HISTBLOCKS 4
#define KEBLOCKS 8
#define CORRBX 128                 // corr blocks = CORRBX*JSPLIT = 512
#define NCORR (CORRBX * JSPLIT)

// ws layout (float-index offsets)
#define WS_F 0                     // 16129 floats (pad to 16384)
#define WS_HIST 16384              // 4*4096 u32
#define WS_PART 33280              // 8320 floats
#define WS_CORR 41728              // 512 floats
#define WS_KE 42368                // 8 floats

#define RSQ __builtin_amdgcn_rsqf

typedef float f32x2 __attribute__((ext_vector_type(2)));

__device__ __forceinline__ f32x2 rsqv(f32x2 a) {
    f32x2 r = {RSQ(a.x), RSQ(a.y)};
    return r;
}

// prep: blocks [0,64): F table = H8 at signed bin offsets (skip the min image);
//       blocks [64,68): position histogram (LDS atomics, 4 partial copies);
//       blocks [68,76): KE partial sums.
__global__ __launch_bounds__(256) void prep_kernel(const float* __restrict__ xy,
                                                   const float* __restrict__ pxy,
                                                   float* __restrict__ F,
                                                   unsigned* __restrict__ hist,
                                                   float* __restrict__ ke_part) {
    const int t = threadIdx.x;
    const int b = blockIdx.x;
    if (b < FBLOCKS) {
        int k = b * 256 + t;
        if (k < FSIZE) {
            float a  = (float)(k % FDIM - 63) * FH;
            float bb = (float)(k / FDIM - 63) * FH;
            int ixm = (__builtin_fabsf(a)  <= 5.0f) ? 0 : (a  > 0.0f ? -1 : 1);
            int iym = (__builtin_fabsf(bb) <= 5.0f) ? 0 : (bb > 0.0f ? -1 : 1);
            float s = 0.0f;
            for (int iy = -1; iy <= 1; ++iy)
                for (int ix = -1; ix <= 1; ++ix) {
                    if (ix == ixm && iy == iym) continue;   // drop min image
                    float xs = __builtin_fmaf(10.0f, (float)ix, a);
                    float ys = __builtin_fmaf(10.0f, (float)iy, bb);
                    s += RSQ(xs * xs + ys * ys);
                }
            F[k] = s;
        }
    } else if (b < FBLOCKS + HISTBLOCKS) {
        __shared__ unsigned lh[NBINS];
        const int hb = b - FBLOCKS;
        for (int k = t; k < NBINS; k += 256) lh[k] = 0u;
        __syncthreads();
        const float2* p2 = (const float2*)xy;
        for (int r = 0; r < 8; ++r) {
            float2 p = p2[hb * 2048 + r * 256 + t];
            int cx = (int)(p.x * BINV); cx = cx > 63 ? 63 : cx;
            int cy = (int)(p.y * BINV); cy = cy > 63 ? 63 : cy;
            atomicAdd(&lh[cy * BGRID + cx], 1u);
        }
        __syncthreads();
        for (int k = t; k < NBINS; k += 256) hist[hb * NBINS + k] = lh[k];
    } else {
        const int kb = b - FBLOCKS - HISTBLOCKS;
        const float4* p4 = (const float4*)pxy;
        float acc = 0.0f;
        for (int k = kb * 256 + t; k < (2 * N) / 4; k += KEBLOCKS * 256) {
            float4 v = p4[k];
            acc += 0.5f * (v.x * v.x + v.y * v.y + v.z * v.z + v.w * v.w);
        }
        for (int off = 32; off > 0; off >>= 1)
            acc += __shfl_down(acc, off, 64);
        __shared__ float ws[4];
        if ((t & 63) == 0) ws[t >> 6] = acc;
        __syncthreads();
        if (t == 0) ke_part[kb] = (ws[0] + ws[1]) + (ws[2] + ws[3]);
    }
}

// main: blocks bx<CORRBX: binned H8 autocorrelation, fully LDS-staged;
//       else: exact min-image 1/r over triangular 128x128 tiles (j-split 4).
__global__ __launch_bounds__(BLOCK) void main_kernel(const float* __restrict__ xy,
                                                     const float* __restrict__ F,
                                                     const unsigned* __restrict__ hist,
                                                     float* __restrict__ partial,
                                                     float* __restrict__ corr_part) {
    const int t = threadIdx.x;
    __shared__ float wsum[BLOCK / 64];
    __shared__ float corrF[8][128];   // 8 F-rows (127 used)
    __shared__ float corrN[8][64];    // 8 n2-rows

    if (blockIdx.x < CORRBX) {
        // cid -> (y1, octet of y2): y1 = cid>>3, y2 in [oc*8, oc*8+8)
        const int cid = blockIdx.x * JSPLIT + blockIdx.y;    // 0..511
        const int y1 = cid >> 3;
        const int y2b = (cid & 7) * 8;
        const int x1 = t & 63;
        const int x2c = t >> 6;                              // 0 or 1
        const int x2base = x2c * 32;

        // stage: 8 F-rows + 8 n2-rows, one barrier, then pure LDS compute
#pragma unroll
        for (int s = 0; s < 8; ++s) {
            if (t < FDIM)
                corrF[s][t] = F[(y1 - (y2b + s) + 63) * FDIM + t];
            if (t < 64) {
                int hi = (y2b + s) * BGRID + t;
                corrN[s][t] = (float)(hist[hi] + hist[NBINS + hi]
                                    + hist[2 * NBINS + hi] + hist[3 * NBINS + hi]);
            }
        }
        int h1 = y1 * BGRID + x1;
        float n1 = (float)(hist[h1] + hist[NBINS + h1]
                         + hist[2 * NBINS + h1] + hist[3 * NBINS + h1]);
        __syncthreads();

        const int fb = 63 + x1 - x2base;
        float acc = 0.0f;
#pragma unroll
        for (int s = 0; s < 8; ++s) {
            const float* Fr = &corrF[s][0];
            const float* Nr = &corrN[s][x2base];
            float sum = 0.0f;
#pragma unroll 8
            for (int k = 0; k < 32; ++k)
                sum = __builtin_fmaf(Nr[k], Fr[fb - k], sum);   // Nr: broadcast; Fr: stride-1
            acc += sum;
        }
        acc *= n1;
        for (int off = 32; off > 0; off >>= 1)
            acc += __shfl_down(acc, off, 64);
        if ((t & 63) == 0) wsum[t >> 6] = acc;
        __syncthreads();
        if (t == 0) corr_part[cid] = wsum[0] + wsum[1];
        return;
    }

    // ---- pe: exact min-image part ----
    int rem = blockIdx.x - CORRBX;
    int ib = 0;
    while (rem >= NB - ib) { rem -= NB - ib; ++ib; }
    const int jb = ib + rem;

    const int i = ib * ITILE + t;
    const float2 pi = ((const float2*)xy)[i];
    const f32x2 xiv = {pi.x, pi.x};
    const f32x2 yiv = {pi.y, pi.y};

    const int j0 = jb * ITILE + blockIdx.y * JSUB;
    const float4* __restrict__ xy4 = (const float4*)xy;     // (x0,y0,x1,y1) pairs
    const int jq = j0 >> 1;

    float a;
    if (ib == jb) {
        f32x2 acc = {0.0f, 0.0f};
#pragma unroll 8
        for (int q = 0; q < JSUB / 2; ++q) {
            float4 pj = xy4[jq + q];
            f32x2 dx = xiv - (f32x2){pj.x, pj.z};
            f32x2 dy = yiv - (f32x2){pj.y, pj.w};
            float tx0 = __builtin_fabsf(dx.x) - 5.0f;
            float tx1 = __builtin_fabsf(dx.y) - 5.0f;
            float ty0 = __builtin_fabsf(dy.x) - 5.0f;
            float ty1 = __builtin_fabsf(dy.y) - 5.0f;
            f32x2 ux = {5.0f - __builtin_fabsf(tx0), 5.0f - __builtin_fabsf(tx1)};
            f32x2 uy = {5.0f - __builtin_fabsf(ty0), 5.0f - __builtin_fabsf(ty1)};
            f32x2 r2 = __builtin_elementwise_fma(uy, uy, ux * ux);
            f32x2 rr = rsqv(r2);
            if (i == j0 + 2 * q)     rr.x = 0.0f;   // diagonal fully masked
            if (i == j0 + 2 * q + 1) rr.y = 0.0f;
            acc += rr;
        }
        a = acc.x + acc.y;
    } else {
        f32x2 s0 = {0.0f, 0.0f}, s1 = s0;
#pragma unroll 8
        for (int q = 0; q < JSUB / 2; ++q) {
            float4 pj = xy4[jq + q];                // uniform -> scalar broadcast
            f32x2 dx = xiv - (f32x2){pj.x, pj.z};
            f32x2 dy = yiv - (f32x2){pj.y, pj.w};
            float tx0 = __builtin_fabsf(dx.x) - 5.0f;
            float tx1 = __builtin_fabsf(dx.y) - 5.0f;
            float ty0 = __builtin_fabsf(dy.x) - 5.0f;
            float ty1 = __builtin_fabsf(dy.y) - 5.0f;
            f32x2 ux = {5.0f - __builtin_fabsf(tx0), 5.0f - __builtin_fabsf(tx1)};
            f32x2 uy = {5.0f - __builtin_fabsf(ty0), 5.0f - __builtin_fabsf(ty1)};
            f32x2 r2 = __builtin_elementwise_fma(uy, uy, ux * ux);
            if (q & 1) s1 += rsqv(r2);
            else       s0 += rsqv(r2);
        }
        f32x2 sv = s0 + s1;
        a = 2.0f * (sv.x + sv.y);                   // mirrored (j,i) tile
    }

    for (int off = 32; off > 0; off >>= 1)
        a += __shfl_down(a, off, 64);
    if ((t & 63) == 0) wsum[t >> 6] = a;
    __syncthreads();
    if (t == 0)
        partial[blockIdx.y * NTRI + (blockIdx.x - CORRBX)] = wsum[0] + wsum[1];
}

// finish: pe partials + corr partials + KE − N*F(0) -> out scalar.
__global__ __launch_bounds__(1024) void finish_kernel(const float* __restrict__ partial,
                                                      const float* __restrict__ corr_part,
                                                      const float* __restrict__ ke_part,
                                                      const float* __restrict__ F,
                                                      float* __restrict__ out) {
    const int t = threadIdx.x;
    float acc = 0.0f;
    const float4* p4 = (const float4*)partial;
    for (int k = t; k < NPART / 4; k += 1024) {
        float4 v = p4[k];
        acc += (v.x + v.y) + (v.z + v.w);
    }
    if (t < NCORR) acc += corr_part[t];
    if (t < KEBLOCKS) acc += ke_part[t];
    if (t == 0) acc -= (float)N * F[63 * FDIM + 63];   // remove i==j from corr
    for (int off = 32; off > 0; off >>= 1)
        acc += __shfl_down(acc, off, 64);
    __shared__ float ws[16];
    if ((t & 63) == 0) ws[t >> 6] = acc;
    __syncthreads();
    if (t == 0) {
        float s = 0.0f;
        for (int w = 0; w < 16; ++w) s += ws[w];
        out[0] = s;
    }
}

extern "C" void kernel_launch(void* const* d_in, const int* in_sizes, int n_in,
                              void* d_out, int out_size, void* d_ws, size_t ws_size,
                              hipStream_t stream) {
    const float* xy  = (const float*)d_in[0];
    const float* pxy = (const float*)d_in[1];
    float* out       = (float*)d_out;
    float* wsf       = (float*)d_ws;
    float* F         = wsf + WS_F;
    unsigned* hist   = (unsigned*)(wsf + WS_HIST);
    float* partial   = wsf + WS_PART;
    float* corr_part = wsf + WS_CORR;
    float* ke_part   = wsf + WS_KE;

    prep_kernel<<<FBLOCKS + HISTBLOCKS + KEBLOCKS, 256, 0, stream>>>(xy, pxy, F, hist, ke_part);
    dim3 grid(CORRBX + NTRI, JSPLIT);
    main_kernel<<<grid, BLOCK, 0, stream>>>(xy, F, hist, partial, corr_part);
    finish_kernel<<<1, 1024, 0, stream>>>(partial, corr_part, ke_part, F, out);
}